// Round 3
// baseline (681.138 us; speedup 1.0000x reference)
//
#include <hip/hip_runtime.h>

// B=32 H=8 NQ=64 NK=4096 DIN=512 DV=64 DM=512
// Factorization: out = (att @ values) @ G + bias2,
//   G[e][h*512+c] = sum_dv Wo[e][h*64+dv] * Wv[h*64+dv][c]   (per-head block)
//   bias2[e]     = b_o[e] + sum_d b_v[d]*Wo[e][d]            (softmax rows sum to 1)
// This removes the 128 MB vT intermediate and reads values exactly once.
typedef short bf16x8 __attribute__((ext_vector_type(8)));
typedef float f32x4 __attribute__((ext_vector_type(4)));
typedef float f32x2 __attribute__((ext_vector_type(2)));
typedef unsigned int u32x2 __attribute__((ext_vector_type(2)));
typedef unsigned int u32x4 __attribute__((ext_vector_type(4)));

__device__ __forceinline__ unsigned short f2bf(float f) {
  union { float f; unsigned u; } v; v.f = f;
  unsigned r = v.u + 0x7fffu + ((v.u >> 16) & 1u);   // RNE
  return (unsigned short)(r >> 16);
}

// pack two fp32 -> bf16x2 (round-to-nearest, ties up): 2 v_add + 1 v_perm
__device__ __forceinline__ unsigned int pk2(float a, float b) {
  union { float f; unsigned u; } x, y; x.f = a; y.f = b;
  return __builtin_amdgcn_perm(y.u + 0x8000u, x.u + 0x8000u, 0x07060302u);
}

__device__ __forceinline__ void gld_lds16(const void* g, void* l) {
  __builtin_amdgcn_global_load_lds(
      (const __attribute__((address_space(1))) void*)g,
      (__attribute__((address_space(3))) void*)l, 16, 0, 0);
}

// ---------------------------------------------------------------------------
// prep2: blocks 0-127: Gt[e][h*512+c] (bf16); blocks 128-129: bias2.
__global__ __launch_bounds__(256) void prep2(const float* __restrict__ W_v,
                                             const float* __restrict__ W_o,
                                             const float* __restrict__ b_v,
                                             const float* __restrict__ b_o,
                                             unsigned short* __restrict__ Gtb,
                                             float* __restrict__ bias2) {
  const int bid = blockIdx.x, t = threadIdx.x;
  if (bid < 128) {
    const int h = bid >> 4, et = bid & 15;
    const int e = et * 32 + (t >> 3);
    const int cs = (t & 7) * 64;            // 64-float c-strip
    const float* wv = W_v + (long)(h * 64) * 512 + cs;
    const float* wo = W_o + (long)e * 512 + h * 64;
    f32x4 a[16];
#pragma unroll
    for (int q = 0; q < 16; ++q) a[q] = (f32x4){0.f, 0.f, 0.f, 0.f};
    for (int dv = 0; dv < 64; ++dv) {
      float ws = wo[dv];
      const f32x4* row = (const f32x4*)(wv + (long)dv * 512);
#pragma unroll
      for (int q = 0; q < 16; ++q) a[q] += row[q] * ws;
    }
    unsigned short* g = Gtb + (long)e * 4096 + h * 512 + cs;
#pragma unroll
    for (int q = 0; q < 16; q += 2) {
      u32x4 wb;
      wb[0] = pk2(a[q][0], a[q][1]);
      wb[1] = pk2(a[q][2], a[q][3]);
      wb[2] = pk2(a[q + 1][0], a[q + 1][1]);
      wb[3] = pk2(a[q + 1][2], a[q + 1][3]);
      *(u32x4*)(g + q * 4) = wb;
    }
  } else {
    const int e = (bid - 128) * 256 + t;
    const float* wrow = W_o + (long)e * 512;
    float s = 0.f;
#pragma unroll 4
    for (int d = 0; d < 512; d += 4) {
      f32x4 w = *(const f32x4*)(wrow + d);
      f32x4 bv = *(const f32x4*)(b_v + d);
      s += w[0] * bv[0] + w[1] * bv[1] + w[2] * bv[2] + w[3] * bv[3];
    }
    bias2[e] = s + b_o[e];
  }
}

// ---------------------------------------------------------------------------
// y_gemm: Yn[b][q][h*512+c] = (1/Z) * sum_k exp(a12*a3) * values[b][k][c]
// grid (8 c-tiles of 64, 32 b), 512 threads = 8 waves; wave w == head h.
// A (att) is GENERATED IN-REGISTER directly in MFMA A-fragment layout
// (lane l16 = row, quad = k-octet) -> zero A-LDS traffic, no A staging.
// B (values) is k-major in memory; transposed at stage time: 256 stager
// threads each read a k-PAIR f32x4 (2 rows, 4 cols) and pk2-pack into
// Bs[c][k] rows (40-short rows: 80 B keeps b128 16-B-aligned, ~4-way max).
// values is read exactly once chip-wide (disjoint 64-col slices per block).
__global__ __launch_bounds__(512, 2) void y_gemm(
    const float* __restrict__ att12, const float* __restrict__ att3,
    const float* __restrict__ values, unsigned short* __restrict__ Y) {
  const int nt = blockIdx.x, b = blockIdx.y;
  const int c0 = nt * 64;
  const int t = threadIdx.x, lane = t & 63, w = t >> 6;   // w = wave = head
  const int l16 = lane & 15, quad = lane >> 4;

  __shared__ __align__(16) unsigned short Bs[2][64 * 40];  // 10 KB
  __shared__ float Zs[512];

  const float* Vb   = values + (long)b * (4096L * 512) + c0;
  const float* a12b = att12 + (long)b * 32768 + w * 16;
  const float* a3b  = att3 + (long)(b * 8 + w) * 64 * 256;

  const bool stager = (t < 256);
  const int kp = t >> 4;        // 0..15 for stagers (k-pair index)
  const int cq = t & 15;        // c-quad

  f32x4 acc[4][4];
#pragma unroll
  for (int i = 0; i < 4; ++i)
#pragma unroll
    for (int j = 0; j < 4; ++j) acc[i][j] = (f32x4){0.f, 0.f, 0.f, 0.f};
  float z[4] = {0.f, 0.f, 0.f, 0.f};
  f32x2 a3p0[4], a3p1[4];
  f32x4 v0r, v1r;

  auto loadV = [&](int k0) {
    const float* p = Vb + (long)(k0 + 2 * kp) * 512 + 4 * cq;
    v0r = *(const f32x4*)(p);
    v1r = *(const f32x4*)(p + 512);
  };
  auto packV = [&](int buf) {
#pragma unroll
    for (int i = 0; i < 4; ++i) {
      unsigned pw = pk2(v0r[i], v1r[i]);   // low short = k even, high = k odd
      *(unsigned*)(&Bs[buf][(4 * cq + i) * 40 + 2 * kp]) = pw;
    }
  };
  auto loadA3 = [&](int ch) {
#pragma unroll
    for (int i = 0; i < 4; ++i) {
      const float* ap = a3b + (long)(i * 16 + l16) * 256 + ch * 16 + quad * 2;
      a3p0[i] = *(const f32x2*)(ap);       // cw = quad*2 + {0,1}
      a3p1[i] = *(const f32x2*)(ap + 8);   // cw = 8 + quad*2 + {0,1}
    }
  };

  // one K-step r (BK=32): k = r*32 + quad*8 + e, e=0..7
  //   ch=(k>>8)=r>>3  fh=((k>>6)&3)=(r>>1)&3  cw=(k>>2)&15=8*(r&1)+quad*2+(e>>2)
  auto step = [&](int r, int buf, int sel) {
    const int ch = r >> 3, fh = (r >> 1) & 3;
    const int cwb = sel * 8 + quad * 2;
    const float* xp = a12b + ch * 2048 + cwb * 128 + fh * 4;
    f32x4 x0 = *(const f32x4*)(xp);          // fw 0..3 at cw = cwb
    f32x4 x1 = *(const f32x4*)(xp + 128);    // fw 0..3 at cw = cwb+1
    bf16x8 af[4];
#pragma unroll
    for (int i = 0; i < 4; ++i) {
      f32x2 y = sel ? a3p1[i] : a3p0[i];
      float e0 = __expf(x0[0] * y[0]), e1 = __expf(x0[1] * y[0]);
      float e2 = __expf(x0[2] * y[0]), e3 = __expf(x0[3] * y[0]);
      float e4 = __expf(x1[0] * y[1]), e5 = __expf(x1[1] * y[1]);
      float e6 = __expf(x1[2] * y[1]), e7 = __expf(x1[3] * y[1]);
      z[i] += (e0 + e1) + (e2 + e3) + ((e4 + e5) + (e6 + e7));
      u32x4 ab;
      ab[0] = pk2(e0, e1); ab[1] = pk2(e2, e3);
      ab[2] = pk2(e4, e5); ab[3] = pk2(e6, e7);
      af[i] = *(bf16x8*)&ab;
    }
    __syncthreads();                          // Bs[buf] (packed pre-call) visible
    if (stager && r < 127) loadV((r + 1) * 32);  // in flight across MFMA
    bf16x8 bfv[4];
#pragma unroll
    for (int j = 0; j < 4; ++j)
      bfv[j] = *(const bf16x8*)(&Bs[buf][(j * 16 + l16) * 40 + quad * 8]);
#pragma unroll
    for (int i = 0; i < 4; ++i)
#pragma unroll
      for (int j = 0; j < 4; ++j)
        acc[i][j] = __builtin_amdgcn_mfma_f32_16x16x32_bf16(af[i], bfv[j], acc[i][j], 0, 0, 0);
  };

  if (stager) loadV(0);
  loadA3(0);
  for (int rr = 0; rr < 128; rr += 2) {       // unroll x2: static sel/buf
    if ((rr & 7) == 0 && rr) loadA3(rr >> 3);
    if (stager) packV(0);
    step(rr, 0, 0);
    if (stager) packV(1);
    step(rr + 1, 1, 1);
  }

  // Z: sum the 4 quads (same l16 row) -> every lane holds full row-sum
#pragma unroll
  for (int i = 0; i < 4; ++i) {
    z[i] += __shfl_xor(z[i], 16);
    z[i] += __shfl_xor(z[i], 32);
  }
  if (quad == 0) {
#pragma unroll
    for (int i = 0; i < 4; ++i) Zs[w * 64 + i * 16 + l16] = z[i];
  }
  __syncthreads();

  // normalize + store bf16: Y[(b*64+q)*4096 + w*512 + c0 + col]
  unsigned short* Yb = Y + (long)b * 64 * 4096 + (long)w * 512 + c0;
#pragma unroll
  for (int i = 0; i < 4; ++i) {
#pragma unroll
    for (int r2 = 0; r2 < 4; ++r2) {
      const int q = i * 16 + quad * 4 + r2;
      const float rz = 1.0f / Zs[w * 64 + q];
#pragma unroll
      for (int j = 0; j < 4; ++j)
        Yb[(long)q * 4096 + j * 16 + l16] = f2bf(acc[i][j][r2] * rz);
    }
  }
}

// ---------------------------------------------------------------------------
// Final projection: out[2048][512] = Y (2048x4096 bf16) x Gt^T + bias2
// T4 protocol: triple-buffered stage 2 deep, one raw barrier per K-step.
// Steady FIFO at pre-barrier wait: {S(r):2, S(r+1):2} = 4 -> vmcnt(2).
template <int BM, int BN>
__global__ __launch_bounds__(256, 2) void gemm_bt(
    const unsigned short* __restrict__ A, const unsigned short* __restrict__ Bt,
    float* __restrict__ C, const float* __restrict__ bias,
    int K, int lda, int ldb, int ldc) {
  constexpr int BK = 32;
  const int t = threadIdx.x;
  const int lane = t & 63;
  const int wave = t >> 6;
  const int m0 = blockIdx.y * BM;
  const int n0 = blockIdx.x * BN;

  A += (long)m0 * lda;
  Bt += (long)n0 * ldb;

  __shared__ __align__(16) unsigned short As[3][BM * BK];
  __shared__ __align__(16) unsigned short Bs[3][BN * BK];

  constexpr int TM = BM / 32;
  constexpr int TN = BN / 32;
  const int wm = (wave >> 1) * (BM / 2);
  const int wn = (wave & 1) * (BN / 2);
  const int l16 = lane & 15;
  const int quad = lane >> 4;

  f32x4 acc[TM][TN];
#pragma unroll
  for (int i = 0; i < TM; ++i)
#pragma unroll
    for (int j = 0; j < TN; ++j) acc[i][j] = (f32x4){0.f, 0.f, 0.f, 0.f};

  constexpr int ASHOT = (BM * 4) / 256;
  constexpr int BSHOT = (BN * 4) / 256;
  const int NIT = K / BK;

  auto stage = [&](int rr, int slot) {
    const int k0 = ((rr < NIT) ? rr : 0) * BK;   // clamp: uniform dummy tail
#pragma unroll
    for (int s = 0; s < ASHOT; ++s) {
      int li = s * 256 + t;
      int row = li >> 2, kq = (li & 3) * 8;
      gld_lds16(A + (long)row * lda + k0 + kq,
                (char*)&As[slot][0] + (s * 256 + wave * 64) * 16);
    }
#pragma unroll
    for (int s = 0; s < BSHOT; ++s) {
      int li = s * 256 + t;
      int row = li >> 2, kq = (li & 3) * 8;
      gld_lds16(Bt + (long)row * ldb + k0 + kq,
                (char*)&Bs[slot][0] + (s * 256 + wave * 64) * 16);
    }
  };

  stage(0, 0);
  stage(1, 1);

  int slotR = 0, slotW = 2;
  for (int r = 0; r < NIT; ++r) {
    asm volatile("s_waitcnt vmcnt(2)" ::: "memory");   // stage(r) landed
    __builtin_amdgcn_s_barrier();
    asm volatile("" ::: "memory");
    stage(r + 2, slotW);
    asm volatile("" ::: "memory");
    bf16x8 af[TM], bfv[TN];
#pragma unroll
    for (int i = 0; i < TM; ++i)
      af[i] = *(const bf16x8*)(&As[slotR][(wm + i * 16 + l16) * BK + quad * 8]);
#pragma unroll
    for (int j = 0; j < TN; ++j)
      bfv[j] = *(const bf16x8*)(&Bs[slotR][(wn + j * 16 + l16) * BK + quad * 8]);
#pragma unroll
    for (int i = 0; i < TM; ++i)
#pragma unroll
      for (int j = 0; j < TN; ++j)
        acc[i][j] = __builtin_amdgcn_mfma_f32_16x16x32_bf16(af[i], bfv[j], acc[i][j], 0, 0, 0);
    slotR = (slotR == 2) ? 0 : slotR + 1;
    slotW = (slotW == 2) ? 0 : slotW + 1;
  }
  asm volatile("s_waitcnt vmcnt(0)" ::: "memory");   // drain tail dummies

#pragma unroll
  for (int i = 0; i < TM; ++i) {
#pragma unroll
    for (int j = 0; j < TN; ++j) {
      int col = wn + j * 16 + l16;
#pragma unroll
      for (int r = 0; r < 4; ++r) {
        int row = wm + i * 16 + quad * 4 + r;
        C[(long)(m0 + row) * ldc + (n0 + col)] = acc[i][j][r] + bias[n0 + col];
      }
    }
  }
}

// ---------------------------------------------------------------------------
extern "C" void kernel_launch(void* const* d_in, const int* in_sizes, int n_in,
                              void* d_out, int out_size, void* d_ws, size_t ws_size,
                              hipStream_t stream) {
  const float* att12 = (const float*)d_in[0];
  const float* att3  = (const float*)d_in[1];
  const float* values = (const float*)d_in[2];
  const float* W_v = (const float*)d_in[3];
  const float* b_v = (const float*)d_in[4];
  const float* W_o = (const float*)d_in[5];
  const float* b_o = (const float*)d_in[6];
  float* out = (float*)d_out;

  char* ws = (char*)d_ws;
  unsigned short* Y     = (unsigned short*)(ws);               // 16 MB [2048][4096]
  unsigned short* Gtb   = (unsigned short*)(ws + 16777216L);   // 4 MB  [512][4096]
  float*          bias2 = (float*)(ws + 20971520L);            // 2 KB

  prep2<<<dim3(130), dim3(256), 0, stream>>>(W_v, W_o, b_v, b_o, Gtb, bias2);

  y_gemm<<<dim3(8, 32), dim3(512), 0, stream>>>(att12, att3, values, Y);

  gemm_bt<64, 64><<<dim3(8, 32), dim3(256), 0, stream>>>(
      Y, Gtb, out, bias2, 4096, 4096, 4096, 512);

  (void)in_sizes; (void)n_in; (void)out_size; (void)ws_size;
}

// Round 4
// 634.876 us; speedup vs baseline: 1.0729x; 1.0729x over previous
//
#include <hip/hip_runtime.h>

// B=32 H=8 NQ=64 NK=4096 DIN=512 DV=64 DM=512
// out = (att_n @ values) @ G + bias2, fused: y2 computes per-(c-tile,b) the
// normalized Yn tiles AND projects them against G, writing per-c-tile partials.
//   G[e][h*512+c] = sum_dv Wo[e][h*64+dv] * Wv[h*64+dv][c]
//   bias2[e]     = b_o[e] + sum_d b_v[d]*Wo[e][d]   (softmax rows sum to 1)
typedef short bf16x8 __attribute__((ext_vector_type(8)));
typedef float f32x4 __attribute__((ext_vector_type(4)));
typedef float f32x2 __attribute__((ext_vector_type(2)));
typedef unsigned int u32x2 __attribute__((ext_vector_type(2)));
typedef unsigned int u32x4 __attribute__((ext_vector_type(4)));

__device__ __forceinline__ unsigned short f2bf(float f) {
  union { float f; unsigned u; } v; v.f = f;
  unsigned r = v.u + 0x7fffu + ((v.u >> 16) & 1u);   // RNE
  return (unsigned short)(r >> 16);
}

// pack two fp32 -> bf16x2 (round-to-nearest, ties up): 2 v_add + 1 v_perm
__device__ __forceinline__ unsigned int pk2(float a, float b) {
  union { float f; unsigned u; } x, y; x.f = a; y.f = b;
  return __builtin_amdgcn_perm(y.u + 0x8000u, x.u + 0x8000u, 0x07060302u);
}

// ---------------------------------------------------------------------------
// prep2: blocks 0-127: Gt[e][h*512+c] (bf16); blocks 128-129: bias2.
// (verified end-to-end in round 3 -- byte-identical here)
__global__ __launch_bounds__(256) void prep2(const float* __restrict__ W_v,
                                             const float* __restrict__ W_o,
                                             const float* __restrict__ b_v,
                                             const float* __restrict__ b_o,
                                             unsigned short* __restrict__ Gtb,
                                             float* __restrict__ bias2) {
  const int bid = blockIdx.x, t = threadIdx.x;
  if (bid < 128) {
    const int h = bid >> 4, et = bid & 15;
    const int e = et * 32 + (t >> 3);
    const int cs = (t & 7) * 64;            // 64-float c-strip
    const float* wv = W_v + (long)(h * 64) * 512 + cs;
    const float* wo = W_o + (long)e * 512 + h * 64;
    f32x4 a[16];
#pragma unroll
    for (int q = 0; q < 16; ++q) a[q] = (f32x4){0.f, 0.f, 0.f, 0.f};
    for (int dv = 0; dv < 64; ++dv) {
      float ws = wo[dv];
      const f32x4* row = (const f32x4*)(wv + (long)dv * 512);
#pragma unroll
      for (int q = 0; q < 16; ++q) a[q] += row[q] * ws;
    }
    unsigned short* g = Gtb + (long)e * 4096 + h * 512 + cs;
#pragma unroll
    for (int q = 0; q < 16; q += 2) {
      u32x4 wb;
      wb[0] = pk2(a[q][0], a[q][1]);
      wb[1] = pk2(a[q][2], a[q][3]);
      wb[2] = pk2(a[q + 1][0], a[q + 1][1]);
      wb[3] = pk2(a[q + 1][2], a[q + 1][3]);
      *(u32x4*)(g + q * 4) = wb;
    }
  } else {
    const int e = (bid - 128) * 256 + t;
    const float* wrow = W_o + (long)e * 512;
    float s = 0.f;
#pragma unroll 4
    for (int d = 0; d < 512; d += 4) {
      f32x4 w = *(const f32x4*)(wrow + d);
      f32x4 bv = *(const f32x4*)(b_v + d);
      s += w[0] * bv[0] + w[1] * bv[1] + w[2] * bv[2] + w[3] * bv[3];
    }
    bias2[e] = s + b_o[e];
  }
}

// ---------------------------------------------------------------------------
// y2: per (c-tile=64, b): Yn = softmax(att) @ values[:, c-tile] for all 8
// heads (wave=head), then fused projection P[cb] = Yn @ G[:, (h, c-tile)]^T.
// - att generated in-register in MFMA A-frag layout (verified round 3).
// - Bs[64c][32k] XOR-swizzled (granule ^= row&3): ds_write_b128 per row and
//   ds_read_b128 both structurally conflict-free.
// - V-loads and att12 x-loads 2 iterations deep in banked regs (static idx).
// - genexp(r+1) issued after MFMA(r): VALU overlaps MFMA drain.
__global__ __launch_bounds__(512, 2) void y2(
    const float* __restrict__ att12, const float* __restrict__ att3,
    const float* __restrict__ values, const unsigned short* __restrict__ Gtb,
    float* __restrict__ P) {
  const int nt = blockIdx.x, b = blockIdx.y;
  const int c0 = nt * 64;
  const int t = threadIdx.x, lane = t & 63, w = t >> 6;   // w = wave = head
  const int l16 = lane & 15, quad = lane >> 4;

  __shared__ __align__(16) unsigned short Bs[2][64 * 32];   // 8 KB
  __shared__ __align__(16) unsigned short Alds[64 * 512];   // 64 KB
  __shared__ float Zs[512];

  const float* Vb   = values + (long)b * (4096L * 512) + c0;
  const float* a12b = att12 + (long)b * 32768 + w * 16;
  const float* a3b  = att3 + (long)(b * 8 + w) * 64 * 256;

  const bool stager = (t < 256);
  const int sc = t & 63;          // stager: c within tile (coalesced axis)
  const int sko = (t >> 6) & 3;   // stager: k-octet

  f32x4 acc[4][4];
#pragma unroll
  for (int i = 0; i < 4; ++i)
#pragma unroll
    for (int j = 0; j < 4; ++j) acc[i][j] = (f32x4){0.f, 0.f, 0.f, 0.f};
  float z[4] = {0.f, 0.f, 0.f, 0.f};
  f32x2 a3p0[4], a3p1[4];
  float vb0[8], vb1[8];           // V banks (static-indexed)
  f32x4 xA0, xA1, xB0, xB1;       // att12 banks
  u32x4 afp[4];                   // packed A-fragments (exps)

  auto loadA3 = [&](int ch) {
#pragma unroll
    for (int i = 0; i < 4; ++i) {
      const float* ap = a3b + (long)(i * 16 + l16) * 256 + ch * 16 + quad * 2;
      a3p0[i] = *(const f32x2*)(ap);       // cw = quad*2 + {0,1}
      a3p1[i] = *(const f32x2*)(ap + 8);   // cw = 8 + quad*2 + {0,1}
    }
  };
  auto genexp = [&](int sel, f32x4 x0, f32x4 x1) {
#pragma unroll
    for (int i = 0; i < 4; ++i) {
      f32x2 y = sel ? a3p1[i] : a3p0[i];
      float e0 = __expf(x0[0] * y[0]), e1 = __expf(x0[1] * y[0]);
      float e2 = __expf(x0[2] * y[0]), e3 = __expf(x0[3] * y[0]);
      float e4 = __expf(x1[0] * y[1]), e5 = __expf(x1[1] * y[1]);
      float e6 = __expf(x1[2] * y[1]), e7 = __expf(x1[3] * y[1]);
      z[i] += (e0 + e1) + (e2 + e3) + ((e4 + e5) + (e6 + e7));
      afp[i] = (u32x4){pk2(e0, e1), pk2(e2, e3), pk2(e4, e5), pk2(e6, e7)};
    }
  };

// One K-step. BUFc: Bs buffer read by MFMA; BUFn: buffer packed for r+1.
// VBA: bank refilled with loadV(r+2); VBB: bank packed (holds loadV(r+1)).
// XA: bank refilled with x(r+2); XB: bank consumed by genexp(r+1).
#define YSTEP(R, BUFc, BUFn, XA0_, XA1_, XB0_, XB1_, VBA, VBB)                  \
  {                                                                             \
    if (stager) {                                                               \
      if ((R) + 1 < 128) {                                                      \
        u32x4 pw;                                                               \
        pw[0] = pk2(VBB[0], VBB[1]); pw[1] = pk2(VBB[2], VBB[3]);               \
        pw[2] = pk2(VBB[4], VBB[5]); pw[3] = pk2(VBB[6], VBB[7]);               \
        *(u32x4*)(&Bs[BUFn][sc * 32 + ((sko ^ (sc & 3)) << 3)]) = pw;           \
      }                                                                         \
      if ((R) + 2 < 128) {                                                      \
        const float* p = Vb + (long)(((R) + 2) * 32 + sko * 8) * 512 + sc;      \
        _Pragma("unroll") for (int o = 0; o < 8; ++o) VBA[o] = p[o * 512];      \
      }                                                                         \
    }                                                                           \
    if ((R) + 2 < 128) {                                                        \
      const int rn = (R) + 2;                                                   \
      const float* xp = a12b + (rn >> 3) * 2048 +                               \
                        (((rn & 1) * 8 + quad * 2) * 128) + (((rn >> 1) & 3) * 4); \
      XA0_ = *(const f32x4*)(xp); XA1_ = *(const f32x4*)(xp + 128);             \
    }                                                                           \
    if ((((R) + 1) & 7) == 0 && (R) + 1 < 128) loadA3(((R) + 1) >> 3);          \
    bf16x8 bfv[4];                                                              \
    _Pragma("unroll") for (int j = 0; j < 4; ++j)                               \
      bfv[j] = *(const bf16x8*)(&Bs[BUFc][(j * 16 + l16) * 32 +                 \
                                          ((quad ^ (l16 & 3)) << 3)]);          \
    _Pragma("unroll") for (int i = 0; i < 4; ++i) {                             \
      bf16x8 a_ = *(bf16x8*)(&afp[i]);                                          \
      _Pragma("unroll") for (int j = 0; j < 4; ++j)                             \
        acc[i][j] = __builtin_amdgcn_mfma_f32_16x16x32_bf16(a_, bfv[j],         \
                                                            acc[i][j], 0, 0, 0); \
    }                                                                           \
    if ((R) + 1 < 128) genexp(((R) + 1) & 1, XB0_, XB1_);                       \
    __syncthreads();                                                            \
  }

  // prologue
  if (stager) {
    const float* p = Vb + (long)(sko * 8) * 512 + sc;   // loadV(0) -> vb0
#pragma unroll
    for (int o = 0; o < 8; ++o) vb0[o] = p[o * 512];
  }
  loadA3(0);
  {  // loadX(0) -> bankA (r=0: ch=0, fh=0, sel=0)
    const float* xp = a12b + (quad * 2) * 128;
    xA0 = *(const f32x4*)(xp); xA1 = *(const f32x4*)(xp + 128);
  }
  if (stager) {
    u32x4 pw;   // pack(0) -> Bs[0]
    pw[0] = pk2(vb0[0], vb0[1]); pw[1] = pk2(vb0[2], vb0[3]);
    pw[2] = pk2(vb0[4], vb0[5]); pw[3] = pk2(vb0[6], vb0[7]);
    *(u32x4*)(&Bs[0][sc * 32 + ((sko ^ (sc & 3)) << 3)]) = pw;
    const float* p = Vb + (long)(32 + sko * 8) * 512 + sc;   // loadV(1) -> vb1
#pragma unroll
    for (int o = 0; o < 8; ++o) vb1[o] = p[o * 512];
  }
  genexp(0, xA0, xA1);
  {  // loadX(1) -> bankB (r=1: ch=0, fh=0, sel=1)
    const float* xp = a12b + ((8 + quad * 2) * 128);
    xB0 = *(const f32x4*)(xp); xB1 = *(const f32x4*)(xp + 128);
  }
  __syncthreads();   // publish Bs[0]

  for (int rp = 0; rp < 64; ++rp) {
    const int r0 = rp * 2;
    YSTEP(r0, 0, 1, xA0, xA1, xB0, xB1, vb0, vb1);
    YSTEP(r0 + 1, 1, 0, xB0, xB1, xA0, xA1, vb1, vb0);
  }
#undef YSTEP

  // Z: sum the 4 quads (same l16 row) -> every lane holds its rows' sums
#pragma unroll
  for (int i = 0; i < 4; ++i) {
    z[i] += __shfl_xor(z[i], 16);
    z[i] += __shfl_xor(z[i], 32);
  }
  if (quad == 0) {
#pragma unroll
    for (int i = 0; i < 4; ++i) Zs[w * 64 + i * 16 + l16] = z[i];
  }
  __syncthreads();

  // normalize + write Yn into Alds[64 q][512 (h,c')] bf16, XOR-swizzled
  // (granule g ^= q&7 within each row; wave w owns granules [w*8, w*8+8))
#pragma unroll
  for (int i = 0; i < 4; ++i)
#pragma unroll
    for (int r2 = 0; r2 < 4; ++r2) {
      const int q = i * 16 + quad * 4 + r2;
      const float rz = 1.0f / Zs[w * 64 + q];
#pragma unroll
      for (int j = 0; j < 4; ++j) {
        const int gw = w * 8 + j * 2 + (l16 >> 3);
        Alds[q * 512 + ((gw ^ (q & 7)) << 3) + (l16 & 7)] =
            f2bf(acc[i][j][r2] * rz);
      }
    }
  __syncthreads();

  // cooperative projection: wave w -> e-strip [w*64, w*64+64), K = 512 (h,c')
  f32x4 acc2[4][4];
#pragma unroll
  for (int i = 0; i < 4; ++i)
#pragma unroll
    for (int j = 0; j < 4; ++j) acc2[i][j] = (f32x4){0.f, 0.f, 0.f, 0.f};
#pragma unroll
  for (int ks = 0; ks < 16; ++ks) {
    bf16x8 af2[4];
#pragma unroll
    for (int i = 0; i < 4; ++i)
      af2[i] = *(const bf16x8*)(&Alds[(i * 16 + l16) * 512 +
                                      (((ks * 4 + quad) ^ (l16 & 7)) << 3)]);
    const int h = ks >> 1, cp = (ks & 1) * 32 + quad * 8;
    bf16x8 bg[4];
#pragma unroll
    for (int j = 0; j < 4; ++j)
      bg[j] = *(const bf16x8*)(Gtb + (long)(w * 64 + j * 16 + l16) * 4096 +
                               h * 512 + c0 + cp);
#pragma unroll
    for (int i = 0; i < 4; ++i)
#pragma unroll
      for (int j = 0; j < 4; ++j)
        acc2[i][j] = __builtin_amdgcn_mfma_f32_16x16x32_bf16(af2[i], bg[j],
                                                             acc2[i][j], 0, 0, 0);
  }
  // store f32 partial: P[cb=nt][b*64+q][e], wave strip e = w*64 + j*16 + l16
  float* Pp = P + ((long)nt * 2048 + b * 64) * 512 + w * 64;
#pragma unroll
  for (int i = 0; i < 4; ++i)
#pragma unroll
    for (int j = 0; j < 4; ++j)
#pragma unroll
      for (int r2 = 0; r2 < 4; ++r2)
        Pp[(long)(i * 16 + quad * 4 + r2) * 512 + j * 16 + l16] = acc2[i][j][r2];
}

// ---------------------------------------------------------------------------
// reduceP: out[m][e] = sum_cb P[cb][m][e] + bias2[e]
__global__ __launch_bounds__(256) void reduceP(const float* __restrict__ P,
                                               const float* __restrict__ bias2,
                                               float* __restrict__ out) {
  const long idx = (long)blockIdx.x * 256 + threadIdx.x;   // f32x4 chunks
  const long m = idx >> 7;          // 128 chunks per 512-wide row
  const int e4 = (int)(idx & 127);
  const float* p = P + m * 512 + e4 * 4;
  f32x4 s = *(const f32x4*)(bias2 + e4 * 4);
#pragma unroll
  for (int cb = 0; cb < 8; ++cb) s += *(const f32x4*)(p + (long)cb * 2048 * 512);
  *(f32x4*)(out + m * 512 + e4 * 4) = s;
}

// ---------------------------------------------------------------------------
extern "C" void kernel_launch(void* const* d_in, const int* in_sizes, int n_in,
                              void* d_out, int out_size, void* d_ws, size_t ws_size,
                              hipStream_t stream) {
  const float* att12 = (const float*)d_in[0];
  const float* att3  = (const float*)d_in[1];
  const float* values = (const float*)d_in[2];
  const float* W_v = (const float*)d_in[3];
  const float* b_v = (const float*)d_in[4];
  const float* W_o = (const float*)d_in[5];
  const float* b_o = (const float*)d_in[6];
  float* out = (float*)d_out;

  char* ws = (char*)d_ws;
  float*          P     = (float*)(ws);                      // 32 MB [8][2048][512]
  unsigned short* Gtb   = (unsigned short*)(ws + 33554432L); // 4 MB  [512][4096]
  float*          bias2 = (float*)(ws + 37748736L);          // 2 KB

  prep2<<<dim3(130), dim3(256), 0, stream>>>(W_v, W_o, b_v, b_o, Gtb, bias2);

  y2<<<dim3(8, 32), dim3(512), 0, stream>>>(att12, att3, values, Gtb, P);

  reduceP<<<dim3(1024), dim3(256), 0, stream>>>(P, bias2, out);

  (void)in_sizes; (void)n_in; (void)out_size; (void)ws_size;
}